// Round 7
// baseline (41.631 us; speedup 1.0000x reference)
//
#include <hip/hip_runtime.h>

// Problem constants (match the JAX reference)
constexpr int BATCH      = 256;
constexpr int T          = 100;
constexpr int J          = 32;
constexpr int EDGES      = 101;
constexpr int NBINS      = 100;
constexpr int NPOINTS    = T * J;          // 3200 points per row
constexpr int ROW_FLOATS = NPOINTS * 3;    // 9600 floats per row
constexpr int NREP       = 32;             // histogram replicas
constexpr int NTHREADS   = 1024;           // 16 waves
constexpr int NWAVES     = NTHREADS / 64;
constexpr int TSTRIDE    = 97;             // float2 units per timestep (96 used + 1 pad
                                           // -> half-waves hit disjoint bank sets)
constexpr int TMAIN      = 96;             // 3 rounds x (16 waves x 2 timesteps)
constexpr float EPSF     = 1e-8f;
constexpr float NTOT     = 102400.0f;      // T*J*J = counts.sum()

// Raw v_sqrt_f32 (~1 ulp) — guess only; exact binning via squared-domain thresholds.
__device__ __forceinline__ float sqrt_approx(float s) {
    float r;
    asm("v_sqrt_f32 %0, %1" : "=v"(r) : "v"(s));
    return r;
}

__global__ __launch_bounds__(NTHREADS)
void jsd_kernel(const float* __restrict__ g1all,
                const float* __restrict__ g2all,
                float* __restrict__ out)
{
#pragma clang fp contract(off)
    // Interleaved point layout, float2 units: point (t,c) at t*TSTRIDE + c*3 =
    // {x1y1, x2y2, z1z2} -> 3x ds_read_b64 with imm offsets covers BOTH datasets.
    __shared__ float2 spt[T * TSTRIDE];              // 77,600 B
    __shared__ unsigned int hist[2][NREP][EDGES];    // 25,856 B
    __shared__ float edg[EDGES];                     // edges (epilogue widths)
    __shared__ float sqe[EDGES];                     // squared-domain thresholds m_i
    __shared__ float2 SQ2[NBINS];                    // {m_i, m_{i+1}} pairs
    __shared__ float sred[NWAVES];
    __shared__ float sterm[NBINS];
    __shared__ float s_mx, s_invw;

    const int tid  = threadIdx.x;
    const int row  = blockIdx.x;
    const int wid  = tid >> 6;
    const int lane = tid & 63;
    const int half = lane >> 5;   // which of the wave's 2 timesteps
    const int a    = lane & 31;   // own point index within the timestep
    const int aoff = a * 3;

    const float* g1 = g1all + (size_t)row * ROW_FLOATS;
    const float* g2 = g2all + (size_t)row * ROW_FLOATS;

    // ---- Stage (interleaved, padded timestep stride), zero histograms.
    for (int k = tid; k < NPOINTS; k += NTHREADS) {
        float x1 = g1[3 * k], y1 = g1[3 * k + 1], z1 = g1[3 * k + 2];
        float x2 = g2[3 * k], y2 = g2[3 * k + 1], z2 = g2[3 * k + 2];
        const int base = (k >> 5) * TSTRIDE + (k & 31) * 3;
        spt[base + 0] = make_float2(x1, y1);
        spt[base + 1] = make_float2(x2, y2);
        spt[base + 2] = make_float2(z1, z2);
    }
    for (int k = tid; k < 2 * NREP * EDGES; k += NTHREADS)
        (&hist[0][0][0])[k] = 0u;
    __syncthreads();

    // ---- Pass A: max squared distance (sqrt monotone => sqrt(max)).
    // Rotation enumeration: lane a vs (a+k)&31, k=1..16; own point registered.
    float vmax = 0.0f;
    for (int r = 0; r < TMAIN / (NWAVES * 2); ++r) {
        const int t    = r * (NWAVES * 2) + wid * 2 + half;
        const int base = t * TSTRIDE;
        const float2 o0 = spt[base + aoff];
        const float2 o1 = spt[base + aoff + 1];
        const float2 o2 = spt[base + aoff + 2];
#pragma unroll 4
        for (int k = 1; k <= 16; ++k) {
            const int coff = base + ((a + k) & 31) * 3;
            const float2 c0 = spt[coff];
            const float2 c1 = spt[coff + 1];
            const float2 c2 = spt[coff + 2];
            float dx1 = o0.x - c0.x, dy1 = o0.y - c0.y, dz1 = o2.x - c2.x;
            float s1 = dx1 * dx1 + dy1 * dy1 + dz1 * dz1;   // ((x^2+y^2)+z^2), no FMA
            float dx2 = o1.x - c1.x, dy2 = o1.y - c1.y, dz2 = o2.y - c2.y;
            float s2 = dx2 * dx2 + dy2 * dy2 + dz2 * dz2;
            vmax = fmaxf(vmax, fmaxf(s1, s2));
        }
    }
    // Tail: 4 timesteps x 16 k = 64 (t,k) items; wave w takes items [4w,4w+4),
    // two per wave-iteration (one per half-wave).
#pragma unroll
    for (int j = 0; j < 2; ++j) {
        const int it   = wid * 4 + j * 2 + half;
        const int t    = TMAIN + (it >> 4);
        const int k    = (it & 15) + 1;
        const int base = t * TSTRIDE;
        const float2 o0 = spt[base + aoff];
        const float2 o1 = spt[base + aoff + 1];
        const float2 o2 = spt[base + aoff + 2];
        const int coff = base + ((a + k) & 31) * 3;
        const float2 c0 = spt[coff];
        const float2 c1 = spt[coff + 1];
        const float2 c2 = spt[coff + 2];
        float dx1 = o0.x - c0.x, dy1 = o0.y - c0.y, dz1 = o2.x - c2.x;
        float s1 = dx1 * dx1 + dy1 * dy1 + dz1 * dz1;
        float dx2 = o1.x - c1.x, dy2 = o1.y - c1.y, dz2 = o2.y - c2.y;
        float s2 = dx2 * dx2 + dy2 * dy2 + dz2 * dz2;
        vmax = fmaxf(vmax, fmaxf(s1, s2));
    }
    for (int off = 32; off > 0; off >>= 1)
        vmax = fmaxf(vmax, __shfl_down(vmax, off, 64));
    if (lane == 0) sred[wid] = vmax;
    __syncthreads();
    if (tid == 0) {
        float m = sred[0];
        for (int w = 1; w < NWAVES; ++w) m = fmaxf(m, sred[w]);
        float mx = __fsqrt_rn(m);
        s_mx = mx;
        s_invw = 100.0f / mx;    // guess only — threshold probes are exact
    }
    __syncthreads();
    const float invw = s_invw;

    // edges[i] = mn*w0 + mx*w1, mn == 0 exactly (diagonal pairs) -> mx * w1[i];
    // w1[i] = (float)i * 0.01f, endpoint pinned to 1.0 (validated absmax 0.0).
    if (tid < EDGES) {
        float w1 = (tid == EDGES - 1) ? 1.0f : ((float)tid * 0.01f);
        edg[tid] = s_mx * w1;
    }
    __syncthreads();

    // Squared-domain thresholds: m_i = smallest float y >= 0 with RN(sqrt(y)) >= e[i].
    // Then RN(sqrt(s)) >= e[i] <=> s >= m_i — binning on s is EXACTLY the
    // reference's binning of the RN square-rooted distance (RN-sqrt monotone).
    if (tid < EDGES) {
        float e = edg[tid];
        float y = 0.0f;                              // e[0] == 0 -> m_0 = 0
        if (tid > 0) {
            y = __fmul_rn(e, e);
            for (int it = 0; it < 4 && __fsqrt_rn(y) < e; ++it)
                y = __int_as_float(__float_as_int(y) + 1);   // safety (shouldn't fire)
            for (int it = 0; it < 8; ++it) {
                float py = __int_as_float(__float_as_int(y) - 1);
                if (__fsqrt_rn(py) >= e) y = py; else break;
            }
        }
        sqe[tid] = y;
    }
    __syncthreads();
    if (tid < NBINS) SQ2[tid] = make_float2(sqe[tid], sqe[tid + 1]);
    __syncthreads();

    // ---- Pass B: same enumeration; branch-free exact binning; histogram.
    // k<16: unordered pair counted once -> weight 2; k==16: both sides -> weight 1.
    unsigned int* __restrict__ h1 = &hist[0][a][0];
    unsigned int* __restrict__ h2 = &hist[1][a][0];
    for (int r = 0; r < TMAIN / (NWAVES * 2); ++r) {
        const int t    = r * (NWAVES * 2) + wid * 2 + half;
        const int base = t * TSTRIDE;
        const float2 o0 = spt[base + aoff];
        const float2 o1 = spt[base + aoff + 1];
        const float2 o2 = spt[base + aoff + 2];
#pragma unroll 4
        for (int k = 1; k <= 16; ++k) {
            const int coff = base + ((a + k) & 31) * 3;
            const float2 c0 = spt[coff];
            const float2 c1 = spt[coff + 1];
            const float2 c2 = spt[coff + 2];
            float dx1 = o0.x - c0.x, dy1 = o0.y - c0.y, dz1 = o2.x - c2.x;
            float s1 = dx1 * dx1 + dy1 * dy1 + dz1 * dz1;
            float dx2 = o1.x - c1.x, dy2 = o1.y - c1.y, dz2 = o2.y - c2.y;
            float s2 = dx2 * dx2 + dy2 * dy2 + dz2 * dz2;

            int i1 = (int)(sqrt_approx(s1) * invw);
            int i2 = (int)(sqrt_approx(s2) * invw);
            i1 = i1 < 0 ? 0 : (i1 > 99 ? 99 : i1);
            i2 = i2 < 0 ? 0 : (i2 > 99 ? 99 : i2);
            float2 t1 = SQ2[i1];
            float2 t2 = SQ2[i2];
            i1 += (s1 >= t1.y) ? 1 : 0;              // exclusive with the decrement
            i1 -= (s1 <  t1.x) ? 1 : 0;
            i2 += (s2 >= t2.y) ? 1 : 0;
            i2 -= (s2 <  t2.x) ? 1 : 0;
            i1 = i1 > 99 ? 99 : i1;                  // == reference clip to NBINS-1
            i2 = i2 > 99 ? 99 : i2;

            const unsigned int wgt = (k < 16) ? 2u : 1u;
            atomicAdd(&h1[i1], wgt);
            atomicAdd(&h2[i2], wgt);
        }
    }
#pragma unroll
    for (int j = 0; j < 2; ++j) {
        const int it   = wid * 4 + j * 2 + half;
        const int t    = TMAIN + (it >> 4);
        const int k    = (it & 15) + 1;
        const int base = t * TSTRIDE;
        const float2 o0 = spt[base + aoff];
        const float2 o1 = spt[base + aoff + 1];
        const float2 o2 = spt[base + aoff + 2];
        const int coff = base + ((a + k) & 31) * 3;
        const float2 c0 = spt[coff];
        const float2 c1 = spt[coff + 1];
        const float2 c2 = spt[coff + 2];
        float dx1 = o0.x - c0.x, dy1 = o0.y - c0.y, dz1 = o2.x - c2.x;
        float s1 = dx1 * dx1 + dy1 * dy1 + dz1 * dz1;
        float dx2 = o1.x - c1.x, dy2 = o1.y - c1.y, dz2 = o2.y - c2.y;
        float s2 = dx2 * dx2 + dy2 * dy2 + dz2 * dz2;

        int i1 = (int)(sqrt_approx(s1) * invw);
        int i2 = (int)(sqrt_approx(s2) * invw);
        i1 = i1 < 0 ? 0 : (i1 > 99 ? 99 : i1);
        i2 = i2 < 0 ? 0 : (i2 > 99 ? 99 : i2);
        float2 t1 = SQ2[i1];
        float2 t2 = SQ2[i2];
        i1 += (s1 >= t1.y) ? 1 : 0;
        i1 -= (s1 <  t1.x) ? 1 : 0;
        i2 += (s2 >= t2.y) ? 1 : 0;
        i2 -= (s2 <  t2.x) ? 1 : 0;
        i1 = i1 > 99 ? 99 : i1;
        i2 = i2 > 99 ? 99 : i2;

        const unsigned int wgt = (k < 16) ? 2u : 1u;
        atomicAdd(&h1[i1], wgt);
        atomicAdd(&h2[i2], wgt);
    }
    __syncthreads();

    // ---- Final: densities + JSD terms; serial 100-add sum (bit-exact).
    if (tid < NBINS) {
        unsigned int c1 = 0, c2 = 0;
        for (int rr = 0; rr < NREP; ++rr) { c1 += hist[0][rr][tid]; c2 += hist[1][rr][tid]; }
        if (tid == 0) { c1 += T * J; c2 += T * J; }  // diagonal zeros -> bin 0

        float w   = edg[tid + 1] - edg[tid];         // jnp.diff(edges)
        float den = __fmul_rn(NTOT, w);
        float px  = __fdiv_rn((float)c1, den);
        float qx  = __fdiv_rn((float)c2, den);
        float m   = (px + qx) * 0.5f;
        float lm  = logf(m + EPSF);
        float term = px * (logf(px + EPSF) - lm) + qx * (logf(qx + EPSF) - lm);
        sterm[tid] = term;
    }
    __syncthreads();
    if (tid == 0) {
        float acc = 0.0f;
        for (int i = 0; i < NBINS; ++i) acc += sterm[i];
        out[row] = acc * 0.5f;
    }
}

extern "C" void kernel_launch(void* const* d_in, const int* in_sizes, int n_in,
                              void* d_out, int out_size, void* d_ws, size_t ws_size,
                              hipStream_t stream) {
    const float* d1 = (const float*)d_in[0];
    const float* d2 = (const float*)d_in[1];
    float* out = (float*)d_out;
    jsd_kernel<<<BATCH, NTHREADS, 0, stream>>>(d1, d2, out);
}